// Round 4
// baseline (155.394 us; speedup 1.0000x reference)
//
#include <hip/hip_runtime.h>

// Problem constants (match reference)
#define BATCH   4096
#define DIM     64
#define NTOT    (BATCH * DIM * DIM)   // 16,777,216 fp32 per tensor
#define NVEC    (NTOT / 4)            // 4,194,304 float4s
#define MRANK   32
#define GAMMA_C   0.1f
#define LAMBDA2_C 0.1f

#define THREADS 256
#define BLOCKS  1024
#define STRIDE  (BLOCKS * THREADS)    // 262,144
#define ITERS   (NVEC / STRIDE)       // 16 float4-pairs per thread — exact fit

// ---------------------------------------------------------------------------
// Kernel 1: per-block partial sum of (pred-true)^2.
// All 32 global_load_dwordx4 (16 pairs) issued BEFORE any compute —
// __builtin_amdgcn_sched_barrier(0) pins the boundary so the scheduler
// cannot re-interleave loads with uses to shrink live ranges (R3 failure:
// requested 16-deep preload, compiler delivered VGPR=32 ≈ 4-deep).
// ~128 VGPRs of load data; __launch_bounds__(256,2) permits up to 256.
// ---------------------------------------------------------------------------
__global__ void __launch_bounds__(THREADS, 2)
partial_sumsq_kernel(const float4* __restrict__ p, const float4* __restrict__ t,
                     float* __restrict__ partials) {
    const int tid = blockIdx.x * THREADS + threadIdx.x;

    float4 a[ITERS], b[ITERS];
    #pragma unroll
    for (int k = 0; k < ITERS; ++k) a[k] = p[tid + k * STRIDE];
    #pragma unroll
    for (int k = 0; k < ITERS; ++k) b[k] = t[tid + k * STRIDE];

    // Hard scheduling fence: nothing crosses. All 32 loads are now issued.
    __builtin_amdgcn_sched_barrier(0);

    float acc0 = 0.0f, acc1 = 0.0f, acc2 = 0.0f, acc3 = 0.0f;
    #pragma unroll
    for (int k = 0; k < ITERS; ++k) {
        float dx = a[k].x - b[k].x;
        float dy = a[k].y - b[k].y;
        float dz = a[k].z - b[k].z;
        float dw = a[k].w - b[k].w;
        acc0 += dx * dx;
        acc1 += dy * dy;
        acc2 += dz * dz;
        acc3 += dw * dw;
    }
    float acc = (acc0 + acc1) + (acc2 + acc3);

    #pragma unroll
    for (int off = 32; off > 0; off >>= 1)
        acc += __shfl_down(acc, off, 64);

    __shared__ float smem[THREADS / 64];
    const int wid  = threadIdx.x >> 6;
    const int lane = threadIdx.x & 63;
    if (lane == 0) smem[wid] = acc;
    __syncthreads();
    if (threadIdx.x == 0)
        partials[blockIdx.x] = smem[0] + smem[1] + smem[2] + smem[3];
}

// ---------------------------------------------------------------------------
// Kernel 2: one block. Reduce 1024 partials; gather 32x2 traces (256 threads,
// 8 diag elements each); rank loss on wave 0; write the 3 outputs.
// ---------------------------------------------------------------------------
__global__ void __launch_bounds__(THREADS)
finish_kernel(const float* __restrict__ p, const float* __restrict__ t,
              const float* __restrict__ partials, float* __restrict__ out) {
    const int tid = threadIdx.x;

    // --- reduce partials: BLOCKS/THREADS per thread ---
    float s = 0.0f;
    #pragma unroll
    for (int k = 0; k < BLOCKS / THREADS; ++k)
        s += partials[tid + k * THREADS];

    // --- trace gather (independent loads, overlap with the above) ---
    const int mat  = tid >> 3;   // 0..31
    const int part = tid & 7;    // 0..7
    float tp = 0.0f, tr = 0.0f;
    #pragma unroll
    for (int i = 0; i < 8; ++i) {
        const int j = part * 8 + i;
        const size_t off = (size_t)mat * (DIM * DIM) + (size_t)j * (DIM + 1);
        tp += p[off];
        tr += t[off];
    }

    // block-reduce sumsq
    #pragma unroll
    for (int off = 32; off > 0; off >>= 1)
        s += __shfl_down(s, off, 64);
    __shared__ float smem[THREADS / 64];
    const int wid  = tid >> 6;
    const int lane = tid & 63;
    if (lane == 0) smem[wid] = s;

    // per-matrix traces via LDS
    __shared__ float redp[THREADS], redt[THREADS];
    redp[tid] = tp;
    redt[tid] = tr;
    __syncthreads();

    __shared__ float sp[MRANK], st[MRANK];
    if (tid < MRANK) {
        float s1 = 0.0f, s2 = 0.0f;
        #pragma unroll
        for (int i = 0; i < 8; ++i) {
            s1 += redp[tid * 8 + i];
            s2 += redt[tid * 8 + i];
        }
        sp[tid] = s1;
        st[tid] = s2;
    }
    __syncthreads();

    float racc = 0.0f;
    if (tid < MRANK) {
        const float pi = sp[tid];
        const float ti = st[tid];
        for (int j = tid + 1; j < MRANK; ++j) {
            float dt = ti - st[j];
            float dp = pi - sp[j];
            float c = 0.0f;
            if (dt > 0.0f)      c = fmaxf(-dp + GAMMA_C, 0.0f);
            else if (dt < 0.0f) c = fmaxf( dp + GAMMA_C, 0.0f);
            racc += c;
        }
    }
    if (tid < 64) {
        #pragma unroll
        for (int off = 32; off > 0; off >>= 1)
            racc += __shfl_down(racc, off, 64);
        if (tid == 0) {
            float total_ss = smem[0] + smem[1] + smem[2] + smem[3];
            float eff  = total_ss / (float)NTOT;
            float rank = racc / 496.0f;   // 32*31/2 pairs
            out[0] = eff + LAMBDA2_C * rank;
            out[1] = eff;
            out[2] = rank;
        }
    }
}

extern "C" void kernel_launch(void* const* d_in, const int* in_sizes, int n_in,
                              void* d_out, int out_size, void* d_ws, size_t ws_size,
                              hipStream_t stream) {
    const float* pred = (const float*)d_in[0];
    const float* tru  = (const float*)d_in[1];
    float* out = (float*)d_out;
    float* ws  = (float*)d_ws;   // BLOCKS floats of partials — fully
                                 // overwritten by kernel 1 every call.

    partial_sumsq_kernel<<<BLOCKS, THREADS, 0, stream>>>(
        (const float4*)pred, (const float4*)tru, ws);

    finish_kernel<<<1, THREADS, 0, stream>>>(pred, tru, ws, out);
}

// Round 5
// 153.925 us; speedup vs baseline: 1.0095x; 1.0095x over previous
//
#include <hip/hip_runtime.h>

// Problem constants (match reference)
#define BATCH   4096
#define DIM     64
#define NTOT    (BATCH * DIM * DIM)   // 16,777,216 fp32 per tensor
#define NVEC    (NTOT / 4)            // 4,194,304 float4s
#define MRANK   32
#define GAMMA_C   0.1f
#define LAMBDA2_C 0.1f

#define THREADS 256
#define BLOCKS  2048
#define STRIDE  (BLOCKS * THREADS)    // 524,288
#define ITERS   (NVEC / STRIDE)       // 8 float4-pairs per thread — exact fit

typedef float v4f __attribute__((ext_vector_type(4)));

// ---------------------------------------------------------------------------
// Kernel 1: per-block partial sum of (pred-true)^2.
// Single change this round: NONTEMPORAL loads (global_load_dwordx4 ... nt)
// for the 134 MB stream — bypass L1/L2 allocation. R3/R4 established the
// ~46 us plateau is invariant to occupancy/VGPR/MLP and to L3-vs-HBM
// residency; remaining candidate mechanism is cache-allocation throughput.
// ---------------------------------------------------------------------------
__global__ void __launch_bounds__(THREADS, 2)
partial_sumsq_kernel(const v4f* __restrict__ p, const v4f* __restrict__ t,
                     float* __restrict__ partials) {
    const int tid = blockIdx.x * THREADS + threadIdx.x;

    v4f a[ITERS], b[ITERS];
    #pragma unroll
    for (int k = 0; k < ITERS; ++k)
        a[k] = __builtin_nontemporal_load(&p[tid + k * STRIDE]);
    #pragma unroll
    for (int k = 0; k < ITERS; ++k)
        b[k] = __builtin_nontemporal_load(&t[tid + k * STRIDE]);

    // Keep all 16 loads issued before any compute.
    __builtin_amdgcn_sched_barrier(0);

    float acc0 = 0.0f, acc1 = 0.0f, acc2 = 0.0f, acc3 = 0.0f;
    #pragma unroll
    for (int k = 0; k < ITERS; ++k) {
        float dx = a[k].x - b[k].x;
        float dy = a[k].y - b[k].y;
        float dz = a[k].z - b[k].z;
        float dw = a[k].w - b[k].w;
        acc0 += dx * dx;
        acc1 += dy * dy;
        acc2 += dz * dz;
        acc3 += dw * dw;
    }
    float acc = (acc0 + acc1) + (acc2 + acc3);

    #pragma unroll
    for (int off = 32; off > 0; off >>= 1)
        acc += __shfl_down(acc, off, 64);

    __shared__ float smem[THREADS / 64];
    const int wid  = threadIdx.x >> 6;
    const int lane = threadIdx.x & 63;
    if (lane == 0) smem[wid] = acc;
    __syncthreads();
    if (threadIdx.x == 0)
        partials[blockIdx.x] = smem[0] + smem[1] + smem[2] + smem[3];
}

// ---------------------------------------------------------------------------
// Kernel 2: one block. Reduce 2048 partials; gather 32x2 traces (256 threads,
// 8 diag elements each); rank loss on wave 0; write the 3 outputs.
// ---------------------------------------------------------------------------
__global__ void __launch_bounds__(THREADS)
finish_kernel(const float* __restrict__ p, const float* __restrict__ t,
              const float* __restrict__ partials, float* __restrict__ out) {
    const int tid = threadIdx.x;

    // --- reduce partials: BLOCKS/THREADS per thread ---
    float s = 0.0f;
    #pragma unroll
    for (int k = 0; k < BLOCKS / THREADS; ++k)
        s += partials[tid + k * THREADS];

    // --- trace gather (independent loads, overlap with the above) ---
    const int mat  = tid >> 3;   // 0..31
    const int part = tid & 7;    // 0..7
    float tp = 0.0f, tr = 0.0f;
    #pragma unroll
    for (int i = 0; i < 8; ++i) {
        const int j = part * 8 + i;
        const size_t off = (size_t)mat * (DIM * DIM) + (size_t)j * (DIM + 1);
        tp += p[off];
        tr += t[off];
    }

    // block-reduce sumsq
    #pragma unroll
    for (int off = 32; off > 0; off >>= 1)
        s += __shfl_down(s, off, 64);
    __shared__ float smem[THREADS / 64];
    const int wid  = tid >> 6;
    const int lane = tid & 63;
    if (lane == 0) smem[wid] = s;

    // per-matrix traces via LDS
    __shared__ float redp[THREADS], redt[THREADS];
    redp[tid] = tp;
    redt[tid] = tr;
    __syncthreads();

    __shared__ float sp[MRANK], st[MRANK];
    if (tid < MRANK) {
        float s1 = 0.0f, s2 = 0.0f;
        #pragma unroll
        for (int i = 0; i < 8; ++i) {
            s1 += redp[tid * 8 + i];
            s2 += redt[tid * 8 + i];
        }
        sp[tid] = s1;
        st[tid] = s2;
    }
    __syncthreads();

    float racc = 0.0f;
    if (tid < MRANK) {
        const float pi = sp[tid];
        const float ti = st[tid];
        for (int j = tid + 1; j < MRANK; ++j) {
            float dt = ti - st[j];
            float dp = pi - sp[j];
            float c = 0.0f;
            if (dt > 0.0f)      c = fmaxf(-dp + GAMMA_C, 0.0f);
            else if (dt < 0.0f) c = fmaxf( dp + GAMMA_C, 0.0f);
            racc += c;
        }
    }
    if (tid < 64) {
        #pragma unroll
        for (int off = 32; off > 0; off >>= 1)
            racc += __shfl_down(racc, off, 64);
        if (tid == 0) {
            float total_ss = smem[0] + smem[1] + smem[2] + smem[3];
            float eff  = total_ss / (float)NTOT;
            float rank = racc / 496.0f;   // 32*31/2 pairs
            out[0] = eff + LAMBDA2_C * rank;
            out[1] = eff;
            out[2] = rank;
        }
    }
}

extern "C" void kernel_launch(void* const* d_in, const int* in_sizes, int n_in,
                              void* d_out, int out_size, void* d_ws, size_t ws_size,
                              hipStream_t stream) {
    const float* pred = (const float*)d_in[0];
    const float* tru  = (const float*)d_in[1];
    float* out = (float*)d_out;
    float* ws  = (float*)d_ws;   // BLOCKS floats of partials — fully
                                 // overwritten by kernel 1 every call.

    partial_sumsq_kernel<<<BLOCKS, THREADS, 0, stream>>>(
        (const v4f*)pred, (const v4f*)tru, ws);

    finish_kernel<<<1, THREADS, 0, stream>>>(pred, tru, ws, out);
}

// Round 6
// 152.198 us; speedup vs baseline: 1.0210x; 1.0114x over previous
//
#include <hip/hip_runtime.h>

// Problem constants (match reference)
#define BATCH   4096
#define DIM     64
#define NTOT    (BATCH * DIM * DIM)   // 16,777,216 fp32 per tensor
#define NVEC    (NTOT / 4)            // 4,194,304 float4s
#define MRANK   32
#define GAMMA_C   0.1f
#define LAMBDA2_C 0.1f

#define THREADS 256
#define BLOCKS  4096
#define STRIDE  (BLOCKS * THREADS)    // 1,048,576
#define ITERS   (NVEC / STRIDE)       // 4 float4-pairs per thread — exact fit

typedef float v4f __attribute__((ext_vector_type(4)));

// ---------------------------------------------------------------------------
// Kernel 1: per-block partial sum of (pred-true)^2.
// R5 finding: nontemporal loads broke the 46 us cache-allocation wall
// (kernel dropped below the harness's 40 us poison fills; fills show the
// true stream ceiling ~6.5 TB/s). This round: 2x resident waves
// (4096 blocks, ITERS=4, ~45 VGPR, launch_bounds(256,4)) to close the
// remaining latency gap toward the ~21 us read-stream floor.
// ---------------------------------------------------------------------------
__global__ void __launch_bounds__(THREADS, 4)
partial_sumsq_kernel(const v4f* __restrict__ p, const v4f* __restrict__ t,
                     float* __restrict__ partials) {
    const int tid = blockIdx.x * THREADS + threadIdx.x;

    v4f a[ITERS], b[ITERS];
    #pragma unroll
    for (int k = 0; k < ITERS; ++k)
        a[k] = __builtin_nontemporal_load(&p[tid + k * STRIDE]);
    #pragma unroll
    for (int k = 0; k < ITERS; ++k)
        b[k] = __builtin_nontemporal_load(&t[tid + k * STRIDE]);

    // Keep all 8 loads issued before any compute.
    __builtin_amdgcn_sched_barrier(0);

    float acc0 = 0.0f, acc1 = 0.0f, acc2 = 0.0f, acc3 = 0.0f;
    #pragma unroll
    for (int k = 0; k < ITERS; ++k) {
        float dx = a[k].x - b[k].x;
        float dy = a[k].y - b[k].y;
        float dz = a[k].z - b[k].z;
        float dw = a[k].w - b[k].w;
        acc0 += dx * dx;
        acc1 += dy * dy;
        acc2 += dz * dz;
        acc3 += dw * dw;
    }
    float acc = (acc0 + acc1) + (acc2 + acc3);

    #pragma unroll
    for (int off = 32; off > 0; off >>= 1)
        acc += __shfl_down(acc, off, 64);

    __shared__ float smem[THREADS / 64];
    const int wid  = threadIdx.x >> 6;
    const int lane = threadIdx.x & 63;
    if (lane == 0) smem[wid] = acc;
    __syncthreads();
    if (threadIdx.x == 0)
        partials[blockIdx.x] = smem[0] + smem[1] + smem[2] + smem[3];
}

// ---------------------------------------------------------------------------
// Kernel 2: one block. Reduce 4096 partials; gather 32x2 traces (256 threads,
// 8 diag elements each); rank loss on wave 0; write the 3 outputs.
// ---------------------------------------------------------------------------
__global__ void __launch_bounds__(THREADS)
finish_kernel(const float* __restrict__ p, const float* __restrict__ t,
              const float* __restrict__ partials, float* __restrict__ out) {
    const int tid = threadIdx.x;

    // --- reduce partials: BLOCKS/THREADS per thread ---
    float s = 0.0f;
    #pragma unroll
    for (int k = 0; k < BLOCKS / THREADS; ++k)
        s += partials[tid + k * THREADS];

    // --- trace gather (independent loads, overlap with the above) ---
    const int mat  = tid >> 3;   // 0..31
    const int part = tid & 7;    // 0..7
    float tp = 0.0f, tr = 0.0f;
    #pragma unroll
    for (int i = 0; i < 8; ++i) {
        const int j = part * 8 + i;
        const size_t off = (size_t)mat * (DIM * DIM) + (size_t)j * (DIM + 1);
        tp += p[off];
        tr += t[off];
    }

    // block-reduce sumsq
    #pragma unroll
    for (int off = 32; off > 0; off >>= 1)
        s += __shfl_down(s, off, 64);
    __shared__ float smem[THREADS / 64];
    const int wid  = tid >> 6;
    const int lane = tid & 63;
    if (lane == 0) smem[wid] = s;

    // per-matrix traces via LDS
    __shared__ float redp[THREADS], redt[THREADS];
    redp[tid] = tp;
    redt[tid] = tr;
    __syncthreads();

    __shared__ float sp[MRANK], st[MRANK];
    if (tid < MRANK) {
        float s1 = 0.0f, s2 = 0.0f;
        #pragma unroll
        for (int i = 0; i < 8; ++i) {
            s1 += redp[tid * 8 + i];
            s2 += redt[tid * 8 + i];
        }
        sp[tid] = s1;
        st[tid] = s2;
    }
    __syncthreads();

    float racc = 0.0f;
    if (tid < MRANK) {
        const float pi = sp[tid];
        const float ti = st[tid];
        for (int j = tid + 1; j < MRANK; ++j) {
            float dt = ti - st[j];
            float dp = pi - sp[j];
            float c = 0.0f;
            if (dt > 0.0f)      c = fmaxf(-dp + GAMMA_C, 0.0f);
            else if (dt < 0.0f) c = fmaxf( dp + GAMMA_C, 0.0f);
            racc += c;
        }
    }
    if (tid < 64) {
        #pragma unroll
        for (int off = 32; off > 0; off >>= 1)
            racc += __shfl_down(racc, off, 64);
        if (tid == 0) {
            float total_ss = smem[0] + smem[1] + smem[2] + smem[3];
            float eff  = total_ss / (float)NTOT;
            float rank = racc / 496.0f;   // 32*31/2 pairs
            out[0] = eff + LAMBDA2_C * rank;
            out[1] = eff;
            out[2] = rank;
        }
    }
}

extern "C" void kernel_launch(void* const* d_in, const int* in_sizes, int n_in,
                              void* d_out, int out_size, void* d_ws, size_t ws_size,
                              hipStream_t stream) {
    const float* pred = (const float*)d_in[0];
    const float* tru  = (const float*)d_in[1];
    float* out = (float*)d_out;
    float* ws  = (float*)d_ws;   // BLOCKS floats of partials — fully
                                 // overwritten by kernel 1 every call.

    partial_sumsq_kernel<<<BLOCKS, THREADS, 0, stream>>>(
        (const v4f*)pred, (const v4f*)tru, ws);

    finish_kernel<<<1, THREADS, 0, stream>>>(pred, tru, ws, out);
}